// Round 4
// baseline (232.022 us; speedup 1.0000x reference)
//
#include <hip/hip_runtime.h>
#include <hip/hip_bf16.h>
#include <math.h>

typedef __attribute__((ext_vector_type(8))) __bf16 bf16x8;
typedef __attribute__((ext_vector_type(4))) __bf16 bf16x4;
typedef __attribute__((ext_vector_type(4))) float f32x4;

#define NTOK 4096
#define DHEAD 32
#define MBIAS 12.0f
#define QSCALE 0.2550316626f   // log2(e)/sqrt(32)
#define SPLIT 8
#define KVCH  (NTOK / SPLIT)   // 512 kv positions per wave

static __device__ __forceinline__ float fexp2(float x) {
    return __builtin_amdgcn_exp2f(x);
}

// ---------------- Kernel A: split x (fp32 [b][c][n]) -> xh/xl (bf16 [b*n][c]) ----------------
__global__ __launch_bounds__(256) void split_x_kernel(const float* __restrict__ x,
                                                      __bf16* __restrict__ xh,
                                                      __bf16* __restrict__ xl)
{
    const int tid  = threadIdx.x;
    const int w    = tid >> 6, lane = tid & 63;
    const int n    = blockIdx.x * 128 + (w >> 1) * 64 + lane;  // global n in [0,8192)
    const int c0   = (w & 1) * 64;
    const int b    = n >> 12;
    const int nn   = n & (NTOK - 1);
    const float* xp = x + ((size_t)b * 128 + c0) * NTOK + nn;
    __bf16* hp = xh + (size_t)n * 128 + c0;
    __bf16* lp = xl + (size_t)n * 128 + c0;
    for (int i0 = 0; i0 < 64; i0 += 8) {
        bf16x8 h8, l8;
        #pragma unroll
        for (int i = 0; i < 8; ++i) {
            float v = xp[(size_t)(i0 + i) * NTOK];
            __bf16 h = (__bf16)v;
            h8[i] = h;
            l8[i] = (__bf16)(v - (float)h);
        }
        *(bf16x8*)(hp + i0) = h8;
        *(bf16x8*)(lp + i0) = l8;
    }
}

// ---------------- Kernel B: QKV projection via split-bf16 MFMA ----------------
// wave tile = 16 o x 32 n ; grid 1536 = 6 otiles * 256 ntiles -> 6 blocks/CU
__global__ __launch_bounds__(256) void qkv_mfma_kernel(const __bf16* __restrict__ xh,
                                                       const __bf16* __restrict__ xl,
                                                       const float* __restrict__ w,
                                                       __bf16* __restrict__ Qo,
                                                       __bf16* __restrict__ Ko,
                                                       __bf16* __restrict__ Vo)
{
    const int bid   = blockIdx.x;        // 1536 = 6 otiles * 256 ntiles
    const int ot    = bid % 6;
    const int ntile = bid / 6;
    const int tid   = threadIdx.x;
    const int wv    = tid >> 6, lane = tid & 63;
    const int g = lane >> 4, ql = lane & 15;
    const int o0 = ot * 64 + wv * 16;
    const int n0 = ntile * 32;

    f32x4 acc[2] = {{0.f,0.f,0.f,0.f},{0.f,0.f,0.f,0.f}};

    #pragma unroll
    for (int kc = 0; kc < 4; ++kc) {
        const float* wp = w + (size_t)(o0 + ql) * 128 + kc * 32 + g * 8;
        f32x4 w0 = *(const f32x4*)wp;
        f32x4 w1 = *(const f32x4*)(wp + 4);
        bf16x8 wh, wl;
        #pragma unroll
        for (int i = 0; i < 4; ++i) {
            float v0 = w0[i], v1 = w1[i];
            __bf16 h0 = (__bf16)v0, h1 = (__bf16)v1;
            wh[i] = h0; wh[4 + i] = h1;
            wl[i] = (__bf16)(v0 - (float)h0);
            wl[4 + i] = (__bf16)(v1 - (float)h1);
        }
        #pragma unroll
        for (int nt = 0; nt < 2; ++nt) {
            const size_t bofs = (size_t)(n0 + nt * 16 + ql) * 128 + kc * 32 + g * 8;
            bf16x8 bh = *(const bf16x8*)(xh + bofs);
            bf16x8 bl = *(const bf16x8*)(xl + bofs);
            acc[nt] = __builtin_amdgcn_mfma_f32_16x16x32_bf16(wh, bh, acc[nt], 0, 0, 0);
            acc[nt] = __builtin_amdgcn_mfma_f32_16x16x32_bf16(wl, bh, acc[nt], 0, 0, 0);
            acc[nt] = __builtin_amdgcn_mfma_f32_16x16x32_bf16(wh, bl, acc[nt], 0, 0, 0);
        }
    }

    const int orow = o0 + 4 * g;   // +r ; branch uniform per wave (64-aligned o splits)
    #pragma unroll
    for (int nt = 0; nt < 2; ++nt) {
        const int ng = n0 + nt * 16 + ql;
        const int b = ng >> 12, nn = ng & (NTOK - 1);
        if (orow < 128) {
            const int h = orow >> 5, d0 = orow & 31;
            bf16x4 q4;
            #pragma unroll
            for (int r = 0; r < 4; ++r) q4[r] = (__bf16)(acc[nt][r] * QSCALE);
            *(bf16x4*)(Qo + ((size_t)(b * 4 + h) * NTOK + nn) * DHEAD + d0) = q4;
        } else if (orow < 256) {
            const int oo = orow - 128, h = oo >> 5, d0 = oo & 31;
            bf16x4 k4;
            #pragma unroll
            for (int r = 0; r < 4; ++r) k4[r] = (__bf16)acc[nt][r];
            *(bf16x4*)(Ko + ((size_t)(b * 4 + h) * NTOK + nn) * DHEAD + d0) = k4;
        } else {
            const int oo = orow - 256, h = oo >> 5, d0 = oo & 31;
            #pragma unroll
            for (int r = 0; r < 4; ++r)
                Vo[((size_t)(b * 4 + h) * DHEAD + d0 + r) * NTOK + nn] = (__bf16)acc[nt][r];
        }
    }
}

// ---------------- Kernel C: flash attention, static-max, split-KV x8, atomic partials ----------------
// grid 8192 one-wave blocks -> target 8 waves/SIMD. No SW prefetch (TLP hides L2).
// S' = q.k*log2e - 12 via MFMA C-input; P = exp2(S'); l via VALU adds + final shfl reduce.
__global__ __launch_bounds__(64, 8) void attn_kernel(const __bf16* __restrict__ Q,
                                                     const __bf16* __restrict__ K,
                                                     const __bf16* __restrict__ VT,
                                                     float* __restrict__ accb,
                                                     float* __restrict__ lb)
{
    const int bid = blockIdx.x;          // 8192
    const int xcd = bid & 7, pos = bid >> 3;
    const int logical = xcd * 1024 + pos;    // XCD k owns bh k (1.25 MB L2 set)
    const int bh  = logical >> 10;
    const int rem = logical & 1023;
    const int qg  = rem >> 3;                // [0,128)
    const int sp  = rem & 7;                 // kv split
    const int lane = threadIdx.x;
    const int g = lane >> 4, ql = lane & 15;
    const __bf16* Qb = Q  + (size_t)bh * NTOK * DHEAD;
    const __bf16* Kb = K  + (size_t)bh * NTOK * DHEAD;
    const __bf16* Vb = VT + (size_t)bh * DHEAD * NTOK;
    const int q0 = qg * 32;

    bf16x8 qf[2];
    qf[0] = *(const bf16x8*)(Qb + (size_t)(q0 + ql) * DHEAD + 8 * g);
    qf[1] = *(const bf16x8*)(Qb + (size_t)(q0 + 16 + ql) * DHEAD + 8 * g);

    f32x4 acc[2][2] = {};        // [qt][dt] numerators of out^T
    float lsum[2] = {0.f, 0.f};  // lane-partial denominators (this lane's 8 kv slots)
    const f32x4 mneg = {-MBIAS, -MBIAS, -MBIAS, -MBIAS};

    const __bf16* krow  = Kb + (size_t)ql * DHEAD + 8 * g;
    const __bf16* vrow0 = Vb + (size_t)ql * NTOK;
    const __bf16* vrow1 = Vb + (size_t)(16 + ql) * NTOK;

    const int base = sp * KVCH;
    for (int kv0 = base; kv0 < base + KVCH; kv0 += 32) {
        bf16x8 kf0 = *(const bf16x8*)(krow + (size_t)kv0 * DHEAD);
        bf16x8 kf1 = *(const bf16x8*)(krow + (size_t)(kv0 + 16) * DHEAD);
        bf16x4 va00 = *(const bf16x4*)(vrow0 + kv0 + 4 * g);
        bf16x4 va01 = *(const bf16x4*)(vrow0 + kv0 + 16 + 4 * g);
        bf16x4 va10 = *(const bf16x4*)(vrow1 + kv0 + 4 * g);
        bf16x4 va11 = *(const bf16x4*)(vrow1 + kv0 + 16 + 4 * g);
        // V^T A-fragments: slot j<4 -> kv0+4g+j ; j>=4 -> kv0+16+4g+(j-4) (matches S^T rows)
        bf16x8 vf0 = __builtin_shufflevector(va00, va01, 0,1,2,3,4,5,6,7);
        bf16x8 vf1 = __builtin_shufflevector(va10, va11, 0,1,2,3,4,5,6,7);

        #pragma unroll
        for (int qt = 0; qt < 2; ++qt) {
            f32x4 s0 = __builtin_amdgcn_mfma_f32_16x16x32_bf16(kf0, qf[qt], mneg, 0, 0, 0);
            f32x4 s1 = __builtin_amdgcn_mfma_f32_16x16x32_bf16(kf1, qf[qt], mneg, 0, 0, 0);
            bf16x8 pf;
            float ps = 0.f;
            #pragma unroll
            for (int r = 0; r < 4; ++r) {
                float e0 = fexp2(s0[r]);
                float e1 = fexp2(s1[r]);
                ps += e0 + e1;
                pf[r]     = (__bf16)e0;
                pf[4 + r] = (__bf16)e1;
            }
            lsum[qt] += ps;
            acc[qt][0] = __builtin_amdgcn_mfma_f32_16x16x32_bf16(vf0, pf, acc[qt][0], 0, 0, 0);
            acc[qt][1] = __builtin_amdgcn_mfma_f32_16x16x32_bf16(vf1, pf, acc[qt][1], 0, 0, 0);
        }
    }

    // reduce l across the 4 g-groups holding each q-col, then atomic-accumulate partials
    lsum[0] += __shfl_xor(lsum[0], 16); lsum[0] += __shfl_xor(lsum[0], 32);
    lsum[1] += __shfl_xor(lsum[1], 16); lsum[1] += __shfl_xor(lsum[1], 32);

    float* ab = accb + (size_t)bh * 32 * NTOK;
    float* lp = lb + (size_t)bh * NTOK;
    #pragma unroll
    for (int qt = 0; qt < 2; ++qt) {
        const int n = q0 + qt * 16 + ql;
        #pragma unroll
        for (int dt = 0; dt < 2; ++dt)
            #pragma unroll
            for (int r = 0; r < 4; ++r)
                atomicAdd(ab + (size_t)(dt * 16 + 4 * g + r) * NTOK + n, acc[qt][dt][r]);
        if (g == 0) atomicAdd(lp + n, lsum[qt]);
    }
}

// ---------------- Kernel D: combine partials -> normalized hi/lo bf16, token-major ----------------
__global__ __launch_bounds__(256) void combine_kernel(const float* __restrict__ accb,
                                                      const float* __restrict__ lb,
                                                      __bf16* __restrict__ oth,
                                                      __bf16* __restrict__ otl)
{
    const int gidx = blockIdx.x * 256 + threadIdx.x;   // [0, 32768) = 8 bh * 4096 n
    const int bh = gidx >> 12, n = gidx & (NTOK - 1);
    const int b = bh >> 2, h = bh & 3;
    const float inv = 1.0f / lb[(size_t)bh * NTOK + n];
    const float* ap = accb + (size_t)bh * 32 * NTOK + n;
    __bf16* hp = oth + ((size_t)b * NTOK + n) * 128 + h * 32;
    __bf16* lp = otl + ((size_t)b * NTOK + n) * 128 + h * 32;
    #pragma unroll
    for (int dgrp = 0; dgrp < 4; ++dgrp) {
        bf16x8 h8, l8;
        #pragma unroll
        for (int i = 0; i < 8; ++i) {
            float v = ap[(size_t)(dgrp * 8 + i) * NTOK] * inv;
            __bf16 hh = (__bf16)v;
            h8[i] = hh;
            l8[i] = (__bf16)(v - (float)hh);
        }
        *(bf16x8*)(hp + dgrp * 8) = h8;
        *(bf16x8*)(lp + dgrp * 8) = l8;
    }
}

// ---------------- Kernel E: output projection via split-bf16 MFMA + bias ----------------
// wave tile = 16 o x 16 n ; grid 1024 -> 4 blocks/CU
__global__ __launch_bounds__(256) void out_mfma_kernel(const __bf16* __restrict__ oh,
                                                       const __bf16* __restrict__ ol,
                                                       const float* __restrict__ w,
                                                       const float* __restrict__ bias,
                                                       float* __restrict__ y)
{
    const int bid   = blockIdx.x;        // 1024 = 2 otiles * 512 ntiles
    const int ot    = bid & 1;
    const int ntile = bid >> 1;
    const int tid   = threadIdx.x;
    const int wv    = tid >> 6, lane = tid & 63;
    const int g = lane >> 4, ql = lane & 15;
    const int o0 = ot * 64 + wv * 16;
    const int n0 = ntile * 16;

    f32x4 acc = {0.f,0.f,0.f,0.f};

    #pragma unroll
    for (int kc = 0; kc < 4; ++kc) {
        const float* wp = w + (size_t)(o0 + ql) * 128 + kc * 32 + g * 8;
        f32x4 w0 = *(const f32x4*)wp;
        f32x4 w1 = *(const f32x4*)(wp + 4);
        bf16x8 wh, wl;
        #pragma unroll
        for (int i = 0; i < 4; ++i) {
            float v0 = w0[i], v1 = w1[i];
            __bf16 h0 = (__bf16)v0, h1 = (__bf16)v1;
            wh[i] = h0; wh[4 + i] = h1;
            wl[i] = (__bf16)(v0 - (float)h0);
            wl[4 + i] = (__bf16)(v1 - (float)h1);
        }
        const size_t bofs = (size_t)(n0 + ql) * 128 + kc * 32 + g * 8;
        bf16x8 bh = *(const bf16x8*)(oh + bofs);
        bf16x8 bl = *(const bf16x8*)(ol + bofs);
        acc = __builtin_amdgcn_mfma_f32_16x16x32_bf16(wh, bh, acc, 0, 0, 0);
        acc = __builtin_amdgcn_mfma_f32_16x16x32_bf16(wl, bh, acc, 0, 0, 0);
        acc = __builtin_amdgcn_mfma_f32_16x16x32_bf16(wh, bl, acc, 0, 0, 0);
    }

    const int orow = o0 + 4 * g;
    const int ng = n0 + ql;
    const int b = ng >> 12, nn = ng & (NTOK - 1);
    #pragma unroll
    for (int r = 0; r < 4; ++r)
        y[((size_t)b * 128 + orow + r) * NTOK + nn] = acc[r] + bias[orow + r];
}

extern "C" void kernel_launch(void* const* d_in, const int* in_sizes, int n_in,
                              void* d_out, int out_size, void* d_ws, size_t ws_size,
                              hipStream_t stream) {
    const float* x     = (const float*)d_in[0];
    const float* w_qkv = (const float*)d_in[1];
    const float* w_out = (const float*)d_in[2];
    const float* b_out = (const float*)d_in[3];
    float* y = (float*)d_out;

    // ws layout (14.125 MB): xh 2M | xl 2M | Q 2M | K 2M | VT 2M | accb 4M | lb 128K
    // oth/otl alias xh/xl (dead after qkv_mfma_kernel).
    char* ws = (char*)d_ws;
    __bf16* xh   = (__bf16*)(ws);
    __bf16* xl   = (__bf16*)(ws + (size_t)2 * 1024 * 1024);
    __bf16* Qb   = (__bf16*)(ws + (size_t)4 * 1024 * 1024);
    __bf16* Kb   = (__bf16*)(ws + (size_t)6 * 1024 * 1024);
    __bf16* Vb   = (__bf16*)(ws + (size_t)8 * 1024 * 1024);
    float*  accb = (float*)(ws + (size_t)10 * 1024 * 1024);
    float*  lbuf = (float*)(ws + (size_t)14 * 1024 * 1024);
    __bf16* oth = xh;
    __bf16* otl = xl;

    hipLaunchKernelGGL(split_x_kernel, dim3(64), dim3(256), 0, stream, x, xh, xl);
    hipLaunchKernelGGL(qkv_mfma_kernel, dim3(1536), dim3(256), 0, stream, xh, xl, w_qkv, Qb, Kb, Vb);
    hipMemsetAsync(accb, 0, (size_t)4 * 1024 * 1024 + 8 * NTOK * sizeof(float), stream);
    hipLaunchKernelGGL(attn_kernel, dim3(8192), dim3(64), 0, stream, Qb, Kb, Vb, accb, lbuf);
    hipLaunchKernelGGL(combine_kernel, dim3(128), dim3(256), 0, stream, accb, lbuf, oth, otl);
    hipLaunchKernelGGL(out_mfma_kernel, dim3(1024), dim3(256), 0, stream, oth, otl, w_out, b_out, y);
}

// Round 6
// 189.646 us; speedup vs baseline: 1.2235x; 1.2235x over previous
//
#include <hip/hip_runtime.h>
#include <hip/hip_bf16.h>
#include <math.h>

typedef __attribute__((ext_vector_type(8))) __bf16 bf16x8;
typedef __attribute__((ext_vector_type(4))) __bf16 bf16x4;
typedef __attribute__((ext_vector_type(4))) float f32x4;

#define NTOK 4096
#define DHEAD 32
#define MBIAS 12.0f
#define QSCALE 0.2550316626f   // log2(e)/sqrt(32)

static __device__ __forceinline__ float fexp2(float x) {
    return __builtin_amdgcn_exp2f(x);
}

// ---------------- Kernel 1: fused QKV projection (fp32 x and w, split-bf16 MFMA) ----------------
// qkv[o][n] = sum_c w[o][c] x[c][n]; both operands hi/lo-split in-register;
// 3 MFMA passes (wh*xh + wl*xh + wh*xl) ~ fp32 accuracy.
// wave tile = 16 o x 32 n; grid 1536 = 6 otiles * 256 ntiles -> 6 blocks/CU.
__global__ __launch_bounds__(256, 6) void qkv_mfma_kernel(const float* __restrict__ x,
                                                          const float* __restrict__ w,
                                                          __bf16* __restrict__ Qo,
                                                          __bf16* __restrict__ Ko,
                                                          __bf16* __restrict__ Vo)
{
    const int bid   = blockIdx.x;        // 1536 = 6 otiles * 256 ntiles
    const int ot    = bid % 6;
    const int ntile = bid / 6;
    const int tid   = threadIdx.x;
    const int wv    = tid >> 6, lane = tid & 63;
    const int g = lane >> 4, ql = lane & 15;
    const int o0 = ot * 64 + wv * 16;
    const int n0 = ntile * 32;

    f32x4 acc[2] = {{0.f,0.f,0.f,0.f},{0.f,0.f,0.f,0.f}};

    #pragma unroll
    for (int kc = 0; kc < 4; ++kc) {
        const float* wp = w + (size_t)(o0 + ql) * 128 + kc * 32 + g * 8;
        f32x4 w0 = *(const f32x4*)wp;
        f32x4 w1 = *(const f32x4*)(wp + 4);
        bf16x8 wh, wl;
        #pragma unroll
        for (int i = 0; i < 4; ++i) {
            float v0 = w0[i], v1 = w1[i];
            __bf16 h0 = (__bf16)v0, h1 = (__bf16)v1;
            wh[i] = h0; wh[4 + i] = h1;
            wl[i] = (__bf16)(v0 - (float)h0);
            wl[4 + i] = (__bf16)(v1 - (float)h1);
        }
        #pragma unroll
        for (int nt = 0; nt < 2; ++nt) {
            const int ng = n0 + nt * 16 + ql;
            const int b = ng >> 12, nn = ng & (NTOK - 1);
            const float* xp = x + ((size_t)b * 128 + kc * 32 + g * 8) * NTOK + nn;
            bf16x8 bh, bl;
            #pragma unroll
            for (int i = 0; i < 8; ++i) {
                float v = xp[(size_t)i * NTOK];
                __bf16 h = (__bf16)v;
                bh[i] = h;
                bl[i] = (__bf16)(v - (float)h);
            }
            acc[nt] = __builtin_amdgcn_mfma_f32_16x16x32_bf16(wh, bh, acc[nt], 0, 0, 0);
            acc[nt] = __builtin_amdgcn_mfma_f32_16x16x32_bf16(wl, bh, acc[nt], 0, 0, 0);
            acc[nt] = __builtin_amdgcn_mfma_f32_16x16x32_bf16(wh, bl, acc[nt], 0, 0, 0);
        }
    }

    const int orow = o0 + 4 * g;   // +r ; branch uniform per wave (64-aligned o splits)
    #pragma unroll
    for (int nt = 0; nt < 2; ++nt) {
        const int ng = n0 + nt * 16 + ql;
        const int b = ng >> 12, nn = ng & (NTOK - 1);
        if (orow < 128) {
            const int h = orow >> 5, d0 = orow & 31;
            bf16x4 q4;
            #pragma unroll
            for (int r = 0; r < 4; ++r) q4[r] = (__bf16)(acc[nt][r] * QSCALE);
            *(bf16x4*)(Qo + ((size_t)(b * 4 + h) * NTOK + nn) * DHEAD + d0) = q4;
        } else if (orow < 256) {
            const int oo = orow - 128, h = oo >> 5, d0 = oo & 31;
            bf16x4 k4;
            #pragma unroll
            for (int r = 0; r < 4; ++r) k4[r] = (__bf16)acc[nt][r];
            *(bf16x4*)(Ko + ((size_t)(b * 4 + h) * NTOK + nn) * DHEAD + d0) = k4;
        } else {
            const int oo = orow - 256, h = oo >> 5, d0 = oo & 31;
            #pragma unroll
            for (int r = 0; r < 4; ++r)
                Vo[((size_t)(b * 4 + h) * DHEAD + d0 + r) * NTOK + nn] = (__bf16)acc[nt][r];
        }
    }
}

// ---------------- Kernel 2: flash attention, static-max, split-KV x8 in-block, LDS reduce ----------------
// 1024 blocks x 512 thr (8 waves). Wave wv handles kv [wv*512, wv*512+512) of the block's
// 32 q-rows; partial numerators/denominators summed across waves in LDS (additive because
// the softmax max is the static MBIAS). No atomics. bh = bid&7 -> XCD-local K/V.
__global__ __launch_bounds__(512, 8) void attn_kernel(const __bf16* __restrict__ Q,
                                                      const __bf16* __restrict__ K,
                                                      const __bf16* __restrict__ VT,
                                                      float* __restrict__ ot)
{
    __shared__ float red[8][1024];   // [wave][(qt*8+dt*4+r)*64 + lane]
    __shared__ float redl[8][32];    // [wave][qt*16+ql]
    const int bid = blockIdx.x;      // 1024
    const int bh  = bid & 7;
    const int qg  = bid >> 3;        // [0,128)
    const int tid = threadIdx.x;
    const int wv  = tid >> 6;        // kv split
    const int lane = tid & 63;
    const int g = lane >> 4, ql = lane & 15;
    const __bf16* Qb = Q  + (size_t)bh * NTOK * DHEAD;
    const __bf16* Kb = K  + (size_t)bh * NTOK * DHEAD;
    const __bf16* Vb = VT + (size_t)bh * DHEAD * NTOK;
    const int q0 = qg * 32;

    bf16x8 qf[2];
    qf[0] = *(const bf16x8*)(Qb + (size_t)(q0 + ql) * DHEAD + 8 * g);
    qf[1] = *(const bf16x8*)(Qb + (size_t)(q0 + 16 + ql) * DHEAD + 8 * g);

    f32x4 acc[2][2] = {};        // [qt][dt] numerators of out^T
    float lsum[2] = {0.f, 0.f};
    const f32x4 mneg = {-MBIAS, -MBIAS, -MBIAS, -MBIAS};

    const __bf16* krow  = Kb + (size_t)ql * DHEAD + 8 * g;
    const __bf16* vrow0 = Vb + (size_t)ql * NTOK;
    const __bf16* vrow1 = Vb + (size_t)(16 + ql) * NTOK;

    const int base = wv * 512;
    for (int kv0 = base; kv0 < base + 512; kv0 += 32) {
        bf16x8 kf0 = *(const bf16x8*)(krow + (size_t)kv0 * DHEAD);
        bf16x8 kf1 = *(const bf16x8*)(krow + (size_t)(kv0 + 16) * DHEAD);
        bf16x4 va00 = *(const bf16x4*)(vrow0 + kv0 + 4 * g);
        bf16x4 va01 = *(const bf16x4*)(vrow0 + kv0 + 16 + 4 * g);
        bf16x4 va10 = *(const bf16x4*)(vrow1 + kv0 + 4 * g);
        bf16x4 va11 = *(const bf16x4*)(vrow1 + kv0 + 16 + 4 * g);
        // V^T A-fragments: slot j<4 -> kv0+4g+j ; j>=4 -> kv0+16+4g+(j-4) (matches S^T rows)
        bf16x8 vf0 = __builtin_shufflevector(va00, va01, 0,1,2,3,4,5,6,7);
        bf16x8 vf1 = __builtin_shufflevector(va10, va11, 0,1,2,3,4,5,6,7);

        #pragma unroll
        for (int qt = 0; qt < 2; ++qt) {
            f32x4 s0 = __builtin_amdgcn_mfma_f32_16x16x32_bf16(kf0, qf[qt], mneg, 0, 0, 0);
            f32x4 s1 = __builtin_amdgcn_mfma_f32_16x16x32_bf16(kf1, qf[qt], mneg, 0, 0, 0);
            bf16x8 pf;
            float ps = 0.f;
            #pragma unroll
            for (int r = 0; r < 4; ++r) {
                float e0 = fexp2(s0[r]);
                float e1 = fexp2(s1[r]);
                ps += e0 + e1;
                pf[r]     = (__bf16)e0;
                pf[4 + r] = (__bf16)e1;
            }
            lsum[qt] += ps;
            acc[qt][0] = __builtin_amdgcn_mfma_f32_16x16x32_bf16(vf0, pf, acc[qt][0], 0, 0, 0);
            acc[qt][1] = __builtin_amdgcn_mfma_f32_16x16x32_bf16(vf1, pf, acc[qt][1], 0, 0, 0);
        }
    }

    // per-wave l: reduce across the 4 g-groups (lanes l, l^16, l^32, l^48)
    lsum[0] += __shfl_xor(lsum[0], 16); lsum[0] += __shfl_xor(lsum[0], 32);
    lsum[1] += __shfl_xor(lsum[1], 16); lsum[1] += __shfl_xor(lsum[1], 32);

    // stage 1: per-wave partials to LDS (lane-consecutive -> conflict-free)
    #pragma unroll
    for (int qt = 0; qt < 2; ++qt)
        #pragma unroll
        for (int dt = 0; dt < 2; ++dt)
            #pragma unroll
            for (int r = 0; r < 4; ++r)
                red[wv][(qt * 8 + dt * 4 + r) * 64 + lane] = acc[qt][dt][r];
    if (lane < 16) {
        redl[wv][ql]      = lsum[0];
        redl[wv][16 + ql] = lsum[1];
    }
    __syncthreads();

    // stage 2: each thread owns 2 of the 1024 elements; sum across 8 waves
    {
        const int e0 = tid * 2;
        float s0 = 0.f, s1 = 0.f;
        #pragma unroll
        for (int w = 0; w < 8; ++w) { s0 += red[w][e0]; s1 += red[w][e0 + 1]; }
        red[0][e0] = s0; red[0][e0 + 1] = s1;
        if (tid < 32) {
            float s = 0.f;
            #pragma unroll
            for (int w = 0; w < 8; ++w) s += redl[w][tid];
            redl[0][tid] = s;
        }
    }
    __syncthreads();

    // stage 3: wave 0 normalizes and stores fp32 out^T [bh][d][n]
    if (wv == 0) {
        float* otb = ot + (size_t)bh * 32 * NTOK + q0;
        const float inv0 = 1.0f / redl[0][ql];
        const float inv1 = 1.0f / redl[0][16 + ql];
        #pragma unroll
        for (int qt = 0; qt < 2; ++qt) {
            const float inv = qt ? inv1 : inv0;
            #pragma unroll
            for (int dt = 0; dt < 2; ++dt)
                #pragma unroll
                for (int r = 0; r < 4; ++r)
                    otb[(size_t)(dt * 16 + 4 * g + r) * NTOK + qt * 16 + ql] =
                        red[0][(qt * 8 + dt * 4 + r) * 64 + lane] * inv;
        }
    }
}

// ---------------- Kernel 3: output projection (fp32 ot and w, split-bf16 MFMA) + bias ----------------
// wave tile = 16 o x 16 n; grid 1024 = 2 otiles * 512 ntiles -> 4 blocks/CU.
__global__ __launch_bounds__(256, 4) void out_mfma_kernel(const float* __restrict__ ot,
                                                          const float* __restrict__ w,
                                                          const float* __restrict__ bias,
                                                          float* __restrict__ y)
{
    const int bid   = blockIdx.x;        // 1024 = 2 otiles * 512 ntiles
    const int otile = bid & 1;
    const int ntile = bid >> 1;
    const int tid   = threadIdx.x;
    const int wv    = tid >> 6, lane = tid & 63;
    const int g = lane >> 4, ql = lane & 15;
    const int o0 = otile * 64 + wv * 16;
    const int n0 = ntile * 16;

    f32x4 acc = {0.f,0.f,0.f,0.f};
    const int ng = n0 + ql;
    const int b = ng >> 12, nn = ng & (NTOK - 1);

    #pragma unroll
    for (int kc = 0; kc < 4; ++kc) {
        const float* wp = w + (size_t)(o0 + ql) * 128 + kc * 32 + g * 8;
        f32x4 w0 = *(const f32x4*)wp;
        f32x4 w1 = *(const f32x4*)(wp + 4);
        bf16x8 wh, wl;
        #pragma unroll
        for (int i = 0; i < 4; ++i) {
            float v0 = w0[i], v1 = w1[i];
            __bf16 h0 = (__bf16)v0, h1 = (__bf16)v1;
            wh[i] = h0; wh[4 + i] = h1;
            wl[i] = (__bf16)(v0 - (float)h0);
            wl[4 + i] = (__bf16)(v1 - (float)h1);
        }
        // ot channel c = kc*32 + g*8 + i lives at row (b*4+kc)*32 + g*8 + i
        const float* op = ot + (((size_t)(b * 4 + kc)) * 32 + g * 8) * NTOK + nn;
        bf16x8 bh, bl;
        #pragma unroll
        for (int i = 0; i < 8; ++i) {
            float v = op[(size_t)i * NTOK];
            __bf16 h = (__bf16)v;
            bh[i] = h;
            bl[i] = (__bf16)(v - (float)h);
        }
        acc = __builtin_amdgcn_mfma_f32_16x16x32_bf16(wh, bh, acc, 0, 0, 0);
        acc = __builtin_amdgcn_mfma_f32_16x16x32_bf16(wl, bh, acc, 0, 0, 0);
        acc = __builtin_amdgcn_mfma_f32_16x16x32_bf16(wh, bl, acc, 0, 0, 0);
    }

    const int orow = o0 + 4 * g;
    #pragma unroll
    for (int r = 0; r < 4; ++r)
        y[((size_t)b * 128 + orow + r) * NTOK + nn] = acc[r] + bias[orow + r];
}

extern "C" void kernel_launch(void* const* d_in, const int* in_sizes, int n_in,
                              void* d_out, int out_size, void* d_ws, size_t ws_size,
                              hipStream_t stream) {
    const float* x     = (const float*)d_in[0];
    const float* w_qkv = (const float*)d_in[1];
    const float* w_out = (const float*)d_in[2];
    const float* b_out = (const float*)d_in[3];
    float* y = (float*)d_out;

    // ws layout (10 MB): Q 2M | K 2M | VT 2M | ot 4M (fp32 out^T [8][32][4096])
    char* ws = (char*)d_ws;
    __bf16* Qb = (__bf16*)(ws);
    __bf16* Kb = (__bf16*)(ws + (size_t)2 * 1024 * 1024);
    __bf16* Vb = (__bf16*)(ws + (size_t)4 * 1024 * 1024);
    float*  ob = (float*)(ws + (size_t)6 * 1024 * 1024);

    hipLaunchKernelGGL(qkv_mfma_kernel, dim3(1536), dim3(256), 0, stream, x, w_qkv, Qb, Kb, Vb);
    hipLaunchKernelGGL(attn_kernel, dim3(1024), dim3(512), 0, stream, Qb, Kb, Vb, ob);
    hipLaunchKernelGGL(out_mfma_kernel, dim3(1024), dim3(256), 0, stream, ob, w_out, b_out, y);
}

// Round 9
// 120.035 us; speedup vs baseline: 1.9330x; 1.5799x over previous
//
#include <hip/hip_runtime.h>
#include <hip/hip_bf16.h>
#include <math.h>

typedef __attribute__((ext_vector_type(8))) __bf16 bf16x8;
typedef __attribute__((ext_vector_type(4))) __bf16 bf16x4;
typedef __attribute__((ext_vector_type(4))) float f32x4;

#define NTOK 4096
#define DHEAD 32
#define MBIAS 12.0f
#define QSCALE 0.2550316626f   // log2(e)/sqrt(32)

static __device__ __forceinline__ float fexp2(float x) {
    return __builtin_amdgcn_exp2f(x);
}

// ---------------- Kernel 1: fused QKV projection (fp32 x and w, split-bf16 MFMA) ----------------
// qkv[o][n] = sum_c w[o][c] x[c][n]; both operands hi/lo-split in-register;
// 3 MFMA passes (wh*xh + wl*xh + wh*xl) ~ fp32 accuracy.
// wave tile = 16 o x 32 n; grid 1536 = 6 otiles * 256 ntiles -> 6 blocks/CU.
// launch_bounds min-waves 4 (VGPR cap 128): do NOT request more — spill danger (R6 lesson).
__global__ __launch_bounds__(256, 4) void qkv_mfma_kernel(const float* __restrict__ x,
                                                          const float* __restrict__ w,
                                                          __bf16* __restrict__ Qo,
                                                          __bf16* __restrict__ Ko,
                                                          __bf16* __restrict__ Vo)
{
    const int bid   = blockIdx.x;        // 1536 = 6 otiles * 256 ntiles
    const int ot    = bid % 6;
    const int ntile = bid / 6;
    const int tid   = threadIdx.x;
    const int wv    = tid >> 6, lane = tid & 63;
    const int g = lane >> 4, ql = lane & 15;
    const int o0 = ot * 64 + wv * 16;
    const int n0 = ntile * 32;

    f32x4 acc[2] = {{0.f,0.f,0.f,0.f},{0.f,0.f,0.f,0.f}};

    #pragma unroll
    for (int kc = 0; kc < 4; ++kc) {
        const float* wp = w + (size_t)(o0 + ql) * 128 + kc * 32 + g * 8;
        f32x4 w0 = *(const f32x4*)wp;
        f32x4 w1 = *(const f32x4*)(wp + 4);
        bf16x8 wh, wl;
        #pragma unroll
        for (int i = 0; i < 4; ++i) {
            float v0 = w0[i], v1 = w1[i];
            __bf16 h0 = (__bf16)v0, h1 = (__bf16)v1;
            wh[i] = h0; wh[4 + i] = h1;
            wl[i] = (__bf16)(v0 - (float)h0);
            wl[4 + i] = (__bf16)(v1 - (float)h1);
        }
        #pragma unroll
        for (int nt = 0; nt < 2; ++nt) {
            const int ng = n0 + nt * 16 + ql;
            const int b = ng >> 12, nn = ng & (NTOK - 1);
            const float* xp = x + ((size_t)b * 128 + kc * 32 + g * 8) * NTOK + nn;
            bf16x8 bh, bl;
            #pragma unroll
            for (int i = 0; i < 8; ++i) {
                float v = xp[(size_t)i * NTOK];
                __bf16 h = (__bf16)v;
                bh[i] = h;
                bl[i] = (__bf16)(v - (float)h);
            }
            acc[nt] = __builtin_amdgcn_mfma_f32_16x16x32_bf16(wh, bh, acc[nt], 0, 0, 0);
            acc[nt] = __builtin_amdgcn_mfma_f32_16x16x32_bf16(wl, bh, acc[nt], 0, 0, 0);
            acc[nt] = __builtin_amdgcn_mfma_f32_16x16x32_bf16(wh, bl, acc[nt], 0, 0, 0);
        }
    }

    const int orow = o0 + 4 * g;   // +r ; branch uniform per wave (64-aligned o splits)
    #pragma unroll
    for (int nt = 0; nt < 2; ++nt) {
        const int ng = n0 + nt * 16 + ql;
        const int b = ng >> 12, nn = ng & (NTOK - 1);
        if (orow < 128) {
            const int h = orow >> 5, d0 = orow & 31;
            bf16x4 q4;
            #pragma unroll
            for (int r = 0; r < 4; ++r) q4[r] = (__bf16)(acc[nt][r] * QSCALE);
            *(bf16x4*)(Qo + ((size_t)(b * 4 + h) * NTOK + nn) * DHEAD + d0) = q4;
        } else if (orow < 256) {
            const int oo = orow - 128, h = oo >> 5, d0 = oo & 31;
            bf16x4 k4;
            #pragma unroll
            for (int r = 0; r < 4; ++r) k4[r] = (__bf16)acc[nt][r];
            *(bf16x4*)(Ko + ((size_t)(b * 4 + h) * NTOK + nn) * DHEAD + d0) = k4;
        } else {
            const int oo = orow - 256, h = oo >> 5, d0 = oo & 31;
            #pragma unroll
            for (int r = 0; r < 4; ++r)
                Vo[((size_t)(b * 4 + h) * DHEAD + d0 + r) * NTOK + nn] = (__bf16)acc[nt][r];
        }
    }
}

// ---------------- Kernel 2: flash attention, static-max, 64 q/wave, split-KV x8 in-block ----------------
// 512 blocks x 512 thr (8 waves) = exactly 2 blocks/CU resident, 4 waves/SIMD.
// Wave wv covers kv [wv*512, wv*512+512) for the block's 64 q-rows; partials summed
// across waves in LDS (additive: softmax max is the static MBIAS). No atomics.
// launch_bounds (512,4): VGPR cap 128, loop needs ~95 -> NO SPILLS (R6's (512,8) spilled).
__global__ __launch_bounds__(512, 4) void attn_kernel(const __bf16* __restrict__ Q,
                                                      const __bf16* __restrict__ K,
                                                      const __bf16* __restrict__ VT,
                                                      float* __restrict__ ot)
{
    __shared__ float red[8][2048];   // [wave][(qt*8+dt*4+r)*64 + lane]
    __shared__ float redl[8][64];    // [wave][qt*16+ql]
    const int bid = blockIdx.x;      // 512
    const int bh  = bid & 7;         // XCD-local head (round-robin dispatch)
    const int qg  = bid >> 3;        // [0,64)
    const int tid = threadIdx.x;
    const int wv  = tid >> 6;        // kv split
    const int lane = tid & 63;
    const int g = lane >> 4, ql = lane & 15;
    const __bf16* Qb = Q  + (size_t)bh * NTOK * DHEAD;
    const __bf16* Kb = K  + (size_t)bh * NTOK * DHEAD;
    const __bf16* Vb = VT + (size_t)bh * DHEAD * NTOK;
    const int q0 = qg * 64;

    bf16x8 qf[4];
    #pragma unroll
    for (int qt = 0; qt < 4; ++qt)
        qf[qt] = *(const bf16x8*)(Qb + (size_t)(q0 + qt * 16 + ql) * DHEAD + 8 * g);

    f32x4 acc[4][2] = {};        // [qt][dt] numerators of out^T
    float lsum[4] = {0.f, 0.f, 0.f, 0.f};
    const f32x4 mneg = {-MBIAS, -MBIAS, -MBIAS, -MBIAS};

    const __bf16* krow  = Kb + (size_t)ql * DHEAD + 8 * g;
    const __bf16* vrow0 = Vb + (size_t)ql * NTOK;
    const __bf16* vrow1 = Vb + (size_t)(16 + ql) * NTOK;

    const int base = wv * 512;
    for (int kv0 = base; kv0 < base + 512; kv0 += 32) {
        bf16x8 kf0 = *(const bf16x8*)(krow + (size_t)kv0 * DHEAD);
        bf16x8 kf1 = *(const bf16x8*)(krow + (size_t)(kv0 + 16) * DHEAD);
        bf16x4 va00 = *(const bf16x4*)(vrow0 + kv0 + 4 * g);
        bf16x4 va01 = *(const bf16x4*)(vrow0 + kv0 + 16 + 4 * g);
        bf16x4 va10 = *(const bf16x4*)(vrow1 + kv0 + 4 * g);
        bf16x4 va11 = *(const bf16x4*)(vrow1 + kv0 + 16 + 4 * g);
        // V^T A-fragments: slot j<4 -> kv0+4g+j ; j>=4 -> kv0+16+4g+(j-4) (matches S^T rows)
        bf16x8 vf0 = __builtin_shufflevector(va00, va01, 0,1,2,3,4,5,6,7);
        bf16x8 vf1 = __builtin_shufflevector(va10, va11, 0,1,2,3,4,5,6,7);

        #pragma unroll
        for (int qt = 0; qt < 4; ++qt) {
            f32x4 s0 = __builtin_amdgcn_mfma_f32_16x16x32_bf16(kf0, qf[qt], mneg, 0, 0, 0);
            f32x4 s1 = __builtin_amdgcn_mfma_f32_16x16x32_bf16(kf1, qf[qt], mneg, 0, 0, 0);
            bf16x8 pf;
            float ps = 0.f;
            #pragma unroll
            for (int r = 0; r < 4; ++r) {
                float e0 = fexp2(s0[r]);
                float e1 = fexp2(s1[r]);
                ps += e0 + e1;
                pf[r]     = (__bf16)e0;
                pf[4 + r] = (__bf16)e1;
            }
            lsum[qt] += ps;
            acc[qt][0] = __builtin_amdgcn_mfma_f32_16x16x32_bf16(vf0, pf, acc[qt][0], 0, 0, 0);
            acc[qt][1] = __builtin_amdgcn_mfma_f32_16x16x32_bf16(vf1, pf, acc[qt][1], 0, 0, 0);
        }
    }

    // per-wave l: reduce across the 4 g-groups (lanes l, l^16, l^32, l^48)
    #pragma unroll
    for (int qt = 0; qt < 4; ++qt) {
        lsum[qt] += __shfl_xor(lsum[qt], 16);
        lsum[qt] += __shfl_xor(lsum[qt], 32);
    }

    // stage 1: per-wave partials to LDS (lane-consecutive -> conflict-free)
    #pragma unroll
    for (int qt = 0; qt < 4; ++qt)
        #pragma unroll
        for (int dt = 0; dt < 2; ++dt)
            #pragma unroll
            for (int r = 0; r < 4; ++r)
                red[wv][(qt * 8 + dt * 4 + r) * 64 + lane] = acc[qt][dt][r];
    if (lane < 16) {
        #pragma unroll
        for (int qt = 0; qt < 4; ++qt) redl[wv][qt * 16 + ql] = lsum[qt];
    }
    __syncthreads();

    // stage 2: each thread owns 4 of the 2048 elements; sum across 8 waves
    {
        const int e0 = tid * 4;
        float s0 = 0.f, s1 = 0.f, s2 = 0.f, s3 = 0.f;
        #pragma unroll
        for (int w = 0; w < 8; ++w) {
            s0 += red[w][e0];     s1 += red[w][e0 + 1];
            s2 += red[w][e0 + 2]; s3 += red[w][e0 + 3];
        }
        red[0][e0] = s0; red[0][e0 + 1] = s1; red[0][e0 + 2] = s2; red[0][e0 + 3] = s3;
        if (tid < 64) {
            float s = 0.f;
            #pragma unroll
            for (int w = 0; w < 8; ++w) s += redl[w][tid];
            redl[0][tid] = s;
        }
    }
    __syncthreads();

    // stage 3: waves 0..3 normalize + store fp32 out^T [bh][d][n]; wave wv handles qt=wv
    if (wv < 4) {
        const int qt = wv;
        float* otb = ot + (size_t)bh * 32 * NTOK + q0;
        const float inv = 1.0f / redl[0][qt * 16 + ql];
        #pragma unroll
        for (int dt = 0; dt < 2; ++dt)
            #pragma unroll
            for (int r = 0; r < 4; ++r)
                otb[(size_t)(dt * 16 + 4 * g + r) * NTOK + qt * 16 + ql] =
                    red[0][(qt * 8 + dt * 4 + r) * 64 + lane] * inv;
    }
}

// ---------------- Kernel 3: output projection (fp32 ot and w, split-bf16 MFMA) + bias ----------------
// wave tile = 16 o x 16 n; grid 1024 = 2 otiles * 512 ntiles -> 4 blocks/CU.
__global__ __launch_bounds__(256, 4) void out_mfma_kernel(const float* __restrict__ ot,
                                                          const float* __restrict__ w,
                                                          const float* __restrict__ bias,
                                                          float* __restrict__ y)
{
    const int bid   = blockIdx.x;        // 1024 = 2 otiles * 512 ntiles
    const int otile = bid & 1;
    const int ntile = bid >> 1;
    const int tid   = threadIdx.x;
    const int wv    = tid >> 6, lane = tid & 63;
    const int g = lane >> 4, ql = lane & 15;
    const int o0 = otile * 64 + wv * 16;
    const int n0 = ntile * 16;

    f32x4 acc = {0.f,0.f,0.f,0.f};
    const int ng = n0 + ql;
    const int b = ng >> 12, nn = ng & (NTOK - 1);

    #pragma unroll
    for (int kc = 0; kc < 4; ++kc) {
        const float* wp = w + (size_t)(o0 + ql) * 128 + kc * 32 + g * 8;
        f32x4 w0 = *(const f32x4*)wp;
        f32x4 w1 = *(const f32x4*)(wp + 4);
        bf16x8 wh, wl;
        #pragma unroll
        for (int i = 0; i < 4; ++i) {
            float v0 = w0[i], v1 = w1[i];
            __bf16 h0 = (__bf16)v0, h1 = (__bf16)v1;
            wh[i] = h0; wh[4 + i] = h1;
            wl[i] = (__bf16)(v0 - (float)h0);
            wl[4 + i] = (__bf16)(v1 - (float)h1);
        }
        // ot channel c = kc*32 + g*8 + i lives at row (b*4+kc)*32 + g*8 + i
        const float* op = ot + (((size_t)(b * 4 + kc)) * 32 + g * 8) * NTOK + nn;
        bf16x8 bh, bl;
        #pragma unroll
        for (int i = 0; i < 8; ++i) {
            float v = op[(size_t)i * NTOK];
            __bf16 h = (__bf16)v;
            bh[i] = h;
            bl[i] = (__bf16)(v - (float)h);
        }
        acc = __builtin_amdgcn_mfma_f32_16x16x32_bf16(wh, bh, acc, 0, 0, 0);
        acc = __builtin_amdgcn_mfma_f32_16x16x32_bf16(wl, bh, acc, 0, 0, 0);
        acc = __builtin_amdgcn_mfma_f32_16x16x32_bf16(wh, bl, acc, 0, 0, 0);
    }

    const int orow = o0 + 4 * g;
    #pragma unroll
    for (int r = 0; r < 4; ++r)
        y[((size_t)b * 128 + orow + r) * NTOK + nn] = acc[r] + bias[orow + r];
}

extern "C" void kernel_launch(void* const* d_in, const int* in_sizes, int n_in,
                              void* d_out, int out_size, void* d_ws, size_t ws_size,
                              hipStream_t stream) {
    const float* x     = (const float*)d_in[0];
    const float* w_qkv = (const float*)d_in[1];
    const float* w_out = (const float*)d_in[2];
    const float* b_out = (const float*)d_in[3];
    float* y = (float*)d_out;

    // ws layout (10 MB): Q 2M | K 2M | VT 2M | ot 4M (fp32 out^T [8][32][4096])
    char* ws = (char*)d_ws;
    __bf16* Qb = (__bf16*)(ws);
    __bf16* Kb = (__bf16*)(ws + (size_t)2 * 1024 * 1024);
    __bf16* Vb = (__bf16*)(ws + (size_t)4 * 1024 * 1024);
    float*  ob = (float*)(ws + (size_t)6 * 1024 * 1024);

    hipLaunchKernelGGL(qkv_mfma_kernel, dim3(1536), dim3(256), 0, stream, x, w_qkv, Qb, Kb, Vb);
    hipLaunchKernelGGL(attn_kernel, dim3(512), dim3(512), 0, stream, Qb, Kb, Vb, ob);
    hipLaunchKernelGGL(out_mfma_kernel, dim3(1024), dim3(256), 0, stream, ob, w_out, b_out, y);
}